// Round 6
// baseline (861.151 us; speedup 1.0000x reference)
//
#include <hip/hip_runtime.h>

// Problem constants (B=16, P=128, D=256, N=256)
#define D_CH 256
#define N_F  256
#define ROWS_TOTAL 2048              // B*P

typedef float f32x4 __attribute__((ext_vector_type(4)));

// Prepass: inverse-permute W into workspace. Wp[d, perm[d,k]] = W[d,k], so
//   y[r,d] = sum_j x[r,d,j] * Wp[d,j]   (contiguous dot, no gather).
__global__ __launch_bounds__(256) void permute_w_kernel(
    const float* __restrict__ W,
    const int*   __restrict__ perm,
    float*       __restrict__ Wp)
{
    const int i = blockIdx.x * 256 + threadIdx.x;   // i = d*256 + k
    const int d = i >> 8;
    Wp[(d << 8) + perm[i]] = W[i];
}

// Main: one block per (b,p) row => each block streams a CONTIGUOUS 256 KB
// slab of x (all 256 channels) and writes the same slab of out — the m13
// copy-like pattern. Wp rows are streamed from L2/L3 (256 KB, hot).
// Wave w handles channels d = w, w+4, w+8, ... (two per iteration for MLP).
__global__ __launch_bounds__(256) void reuse_linear_rows_kernel(
    const float* __restrict__ x,
    const float* __restrict__ Wp,
    const float* __restrict__ bias,
    float*       __restrict__ out)
{
    const int r    = blockIdx.x;            // (b,p) row, 0..2047
    const int lane = threadIdx.x & 63;
    const int wave = threadIdx.x >> 6;      // 0..3

    const size_t rowbase = (size_t)r * D_CH * N_F;   // floats
    const int    li4     = lane * 4;

    for (int s0 = wave; s0 < D_CH; s0 += 8) {
        const int s1 = s0 + 4;

        const size_t xo0 = rowbase + (size_t)s0 * N_F + li4;
        const size_t xo1 = rowbase + (size_t)s1 * N_F + li4;

        // Issue all four loads before consuming any result.
        const f32x4 a0 = *reinterpret_cast<const f32x4*>(x  + xo0);
        const f32x4 a1 = *reinterpret_cast<const f32x4*>(x  + xo1);
        const f32x4 w0 = *reinterpret_cast<const f32x4*>(Wp + (size_t)s0 * N_F + li4);
        const f32x4 w1 = *reinterpret_cast<const f32x4*>(Wp + (size_t)s1 * N_F + li4);

        float p0 = a0.x * w0.x + a0.y * w0.y + a0.z * w0.z + a0.w * w0.w;
        float p1 = a1.x * w1.x + a1.y * w1.y + a1.z * w1.z + a1.w * w1.w;

        // Two interleaved 64-lane butterfly all-reduces.
        #pragma unroll
        for (int m = 32; m >= 1; m >>= 1) {
            p0 += __shfl_xor(p0, m, 64);
            p1 += __shfl_xor(p1, m, 64);
        }

        const float y0 = p0 + bias[s0];
        const float y1 = p1 + bias[s1];
        f32x4 o0; o0.x = o0.y = o0.z = o0.w = y0;
        f32x4 o1; o1.x = o1.y = o1.z = o1.w = y1;
        *reinterpret_cast<f32x4*>(out + xo0) = o0;
        *reinterpret_cast<f32x4*>(out + xo1) = o1;
    }
}

// Fallback (no workspace): previous strided kernel with LDS-scattered weights.
__global__ __launch_bounds__(256) void reuse_linear_chunk_kernel(
    const float* __restrict__ x,
    const float* __restrict__ W,
    const float* __restrict__ bias,
    const int*   __restrict__ perm,
    float*       __restrict__ out)
{
    __shared__ float wp[N_F];
    const int d     = blockIdx.x;
    const int chunk = blockIdx.y;
    const int tid   = threadIdx.x;

    wp[perm[d * N_F + tid]] = W[d * N_F + tid];
    __syncthreads();

    const int lane = tid & 63;
    const int wave = tid >> 6;
    const f32x4 w4 = *reinterpret_cast<const f32x4*>(&wp[lane * 4]);
    const float bv = bias[d];

    const int row0 = chunk * (ROWS_TOTAL / 16) + wave;
    for (int i = 0; i < 32; ++i) {
        const size_t base = ((size_t)(row0 + 4 * i) * D_CH + d) * N_F + lane * 4;
        const f32x4 x4 = *reinterpret_cast<const f32x4*>(x + base);
        float p = x4.x * w4.x + x4.y * w4.y + x4.z * w4.z + x4.w * w4.w;
        #pragma unroll
        for (int m = 32; m >= 1; m >>= 1) p += __shfl_xor(p, m, 64);
        const float y = p + bv;
        f32x4 o; o.x = o.y = o.z = o.w = y;
        *reinterpret_cast<f32x4*>(out + base) = o;
    }
}

extern "C" void kernel_launch(void* const* d_in, const int* in_sizes, int n_in,
                              void* d_out, int out_size, void* d_ws, size_t ws_size,
                              hipStream_t stream) {
    const float* x    = (const float*)d_in[0];
    const float* W    = (const float*)d_in[1];
    const float* bias = (const float*)d_in[2];
    const int*   perm = (const int*)d_in[3];
    float*       out  = (float*)d_out;

    const size_t wp_bytes = (size_t)D_CH * N_F * sizeof(float);   // 256 KB
    if (ws_size >= wp_bytes) {
        float* Wp = (float*)d_ws;
        permute_w_kernel<<<D_CH, 256, 0, stream>>>(W, perm, Wp);
        reuse_linear_rows_kernel<<<ROWS_TOTAL, 256, 0, stream>>>(x, Wp, bias, out);
    } else {
        dim3 grid(D_CH, 16);
        reuse_linear_chunk_kernel<<<grid, 256, 0, stream>>>(x, W, bias, perm, out);
    }
}